// Round 6
// baseline (86.346 us; speedup 1.0000x reference)
//
#include <hip/hip_runtime.h>

// Signature kernel (dyadic order 1, sigma=1) for xs:(16,128,8), ys:(16,128,8) f32.
// One block (256 thr) per pair. Phase 1 (all 4 waves): RBF Gram K (128x128, f32) and
// quarter-scaled 2nd mixed difference in-place in LDS (stride 128, col 127 zeroed).
// Phase 2 (wave 0 only, ZERO barriers): Goursat PDE on the 255x255 refined grid as a
// register wavefront: lane l owns rows 4l+1..4l+4, all at column j = s - 2*l per step.
// Cross-lane handoff: DPP wave_shr1 with old=1.0 (lane0 boundary for free), result
// consumed 2 substeps later (slack >= DPP latency). Inner-loop DS queue holds ONLY
// the inc prefetch ds_reads, double-buffered across a hand-unrolled 2-body iteration
// with STATIC register names (no swap after load -> no lgkmcnt(0) serialization;
// 4 substeps ~ 128cy slack >= ~120cy LDS latency). R4 lesson: per-substep drain of a
// mixed DS queue (bpermute+reads, in-order) was the 227cy/substep critical path.

#define LX 128
#define D  8
#define NB 16
#define NPAIR 95         // 95 iterations x 2 bodies = 190 bodies = substeps 1..380

__device__ __forceinline__ float wave_shr1_or_one(float v) {
    // lane i <- v[lane i-1]; lane 0 <- 1.0f (bound_ctrl=false keeps 'old' operand)
    const int one = 0x3f800000;
    int r = __builtin_amdgcn_update_dpp(one, __float_as_int(v),
                                        0x138 /*wave_shr:1*/, 0xF, 0xF, false);
    return __int_as_float(r);
}

__global__ __launch_bounds__(256)
void sigkernel_kernel(const float* __restrict__ xs,
                      const float* __restrict__ ys,
                      float* __restrict__ out)
{
    __shared__ float sx[LX][D + 1];
    __shared__ float sy[LX][D + 1];
    __shared__ float xsqv[LX];
    __shared__ float ysqv[LX];
    __shared__ float B[LX * LX + 132];   // K (stride 128) then 0.25*diff; +pad for OOB diff reads

    const int t  = threadIdx.x;
    const int bx = blockIdx.x;
    const int by = blockIdx.y;
    const float* xp = xs + bx * (LX * D);
    const float* yp = ys + by * (LX * D);

    // ---- load x, y ----
    for (int e = t; e < LX * D; e += 256) {
        sx[e >> 3][e & 7] = xp[e];
        sy[e >> 3][e & 7] = yp[e];
    }
    __syncthreads();

    // ---- squared norms ----
    if (t < LX) {
        float sxx = 0.f, syy = 0.f;
        #pragma unroll
        for (int k = 0; k < D; ++k) {
            sxx += sx[t][k] * sx[t][k];
            syy += sy[t][k] * sy[t][k];
        }
        xsqv[t] = sxx;
        ysqv[t] = syy;
    }
    __syncthreads();

    // ---- K[i][j] = exp(-0.5*(|x_i|^2+|y_j|^2-2 x_i.y_j)), stride 128 ----
    {
        const int j = t & 127;
        float yr[D];
        #pragma unroll
        for (int k = 0; k < D; ++k) yr[k] = sy[j][k];
        const float ysq = ysqv[j];
        #pragma unroll
        for (int c = 0; c < 64; ++c) {
            const int e = t + c * 256;
            const int i = e >> 7;
            float dot = 0.f;
            #pragma unroll
            for (int k = 0; k < D; ++k) dot += sx[i][k] * yr[k];
            const float sq = xsqv[i] + ysq - 2.0f * dot;
            B[e] = expf(-0.5f * sq);
        }
    }
    __syncthreads();

    // ---- quarter-scaled 2nd mixed diff, in place at stride 128 (no int division) ----
    {
        float rv[64];
        #pragma unroll
        for (int c = 0; c < 64; ++c) {
            const int e = t + c * 256;
            rv[c] = 0.25f * (B[e + 129] + B[e] - B[e + 128] - B[e + 1]);
        }
        __syncthreads();
        #pragma unroll
        for (int c = 0; c < 64; ++c) {
            const int e = t + c * 256;
            const int i = e >> 7, j = e & 127;
            if (i < 127 && j < 127) B[e] = rv[c];
        }
        if (t < 127) B[t * 128 + 127] = 0.f;   // zero word: OOB clamp target
    }
    __syncthreads();

    // ---- waves 1..3 done; wave 0 runs the register wavefront (no more barriers) ----
    if (t >= 64) return;

    const int l = t;
    const int rowa = 2 * l;                               // dyadic row for rows 4l+1, 4l+2
    const int rowb = (2 * l + 1 > 126) ? 126 : 2 * l + 1; // rows 4l+3, 4l+4 (lane 63 dummy)
    const int baseA = rowa * 128;
    const int baseB = rowb * 128;

    float cur0 = 1.f, cur1 = 1.f, cur2 = 1.f, cur3 = 1.f;  // rows 4l+1..4l+4, col j-1
    float h0 = 1.f, h1 = 1.f, h2 = 1.f;                    // neighbor row-4l history

    // body k uses dyadic column q = k - l; OOB -> B[127] == 0 (broadcast, conflict-free)
#define LD(dstA, dstB, q_)                                  \
    {                                                       \
        const int q = (q_);                                 \
        const bool cl = ((unsigned)q > 126u);               \
        dstA = B[cl ? 127 : (baseA + q)];                   \
        dstB = B[cl ? 127 : (baseB + q)];                   \
    }

#define SUBSTEP()                                           \
    {                                                       \
        const float n0 = (h1 + cur0) * c1 - h2   * c2;      \
        const float n1 = (n0 + cur1) * c1 - cur0 * c2;      \
        const float n2 = (n1 + cur2) * c3 - cur1 * c4;      \
        const float n3 = (n2 + cur3) * c3 - cur2 * c4;      \
        cur0 = n0; cur1 = n1; cur2 = n2; cur3 = n3;         \
        const float sh = wave_shr1_or_one(n3);              \
        h2 = h1; h1 = h0; h0 = sh;                          \
    }

#define BODY(ia_, ib_)                                      \
    {                                                       \
        const float ia = (ia_), ib = (ib_);                 \
        const float ea = ia * ia * (1.0f / 12.0f);          \
        const float eb = ib * ib * (1.0f / 12.0f);          \
        const float c1 = 1.0f + 0.5f * ia + ea, c2 = 1.0f - ea; \
        const float c3 = 1.0f + 0.5f * ib + eb, c4 = 1.0f - eb; \
        SUBSTEP();                                          \
        SUBSTEP();                                          \
    }

    // double-buffered inc prefetch: static names, distance 2 bodies (~128cy slack)
    float a0, b0, a1, b1;
    LD(a0, b0, 0 - l);
    LD(a1, b1, 1 - l);

    for (int m = 0; m < NPAIR; ++m) {
        const int k = 2 * m;
        {
            const float ia = a0, ib = b0;      // body k
            LD(a0, b0, k + 2 - l);             // reload for body k+2 (consumed next iter)
            const float ea = ia * ia * (1.0f / 12.0f);
            const float eb = ib * ib * (1.0f / 12.0f);
            const float c1 = 1.0f + 0.5f * ia + ea, c2 = 1.0f - ea;
            const float c3 = 1.0f + 0.5f * ib + eb, c4 = 1.0f - eb;
            SUBSTEP();
            SUBSTEP();
        }
        {
            const float ia = a1, ib = b1;      // body k+1
            LD(a1, b1, k + 3 - l);             // reload for body k+3
            const float ea = ia * ia * (1.0f / 12.0f);
            const float eb = ib * ib * (1.0f / 12.0f);
            const float c1 = 1.0f + 0.5f * ia + ea, c2 = 1.0f - ea;
            const float c3 = 1.0f + 0.5f * ib + eb, c4 = 1.0f - eb;
            SUBSTEP();
            SUBSTEP();
        }
    }

    // K[254][254]: row 254 = lane 63's second row, finished at s = 380
    if (l == 63) out[bx * NB + by] = cur1;
}

extern "C" void kernel_launch(void* const* d_in, const int* in_sizes, int n_in,
                              void* d_out, int out_size, void* d_ws, size_t ws_size,
                              hipStream_t stream)
{
    const float* xs = (const float*)d_in[0];
    const float* ys = (const float*)d_in[1];
    float* out = (float*)d_out;
    dim3 grid(NB, NB);
    dim3 block(256);
    hipLaunchKernelGGL(sigkernel_kernel, grid, block, 0, stream, xs, ys, out);
}

// Round 7
// 80.004 us; speedup vs baseline: 1.0793x; 1.0793x over previous
//
#include <hip/hip_runtime.h>

// Signature kernel (dyadic order 1, sigma=1) for xs:(16,128,8), ys:(16,128,8) f32.
// One block (256 thr) per pair.
//
// Phase 1 (all 4 waves, parallel): compute PDE coefficients DIRECTLY:
//   K on the fly (dots + expf, never stored), d = 2nd mixed diff, inc = d/4,
//   c1 = 1+inc/2+inc^2/12, c2 = 1-inc^2/12. Stored as quads CF[pair][qrot] =
//   (c1 row 2p, c2 row 2p, c1 row 2p+1, c2 row 2p+1), qrot = (q+2p)&127 so the
//   skewed phase-2 read (q_l = k-l) lands on evenly-spread banks.
// Phase 2 (wave 0 only, ZERO barriers): register wavefront, lane l owns PDE rows
//   4l+1..4l+4 at column j = s-2l; per 2-substep body ONE ds_read_b128 fetches all
//   4 coefficients. Cross-lane handoff via DPP wave_shr1 (old=1.0 -> lane-0 boundary
//   free). OOB bodies read a (1,1,1,1) slot -> cells stay inert 1.0, no predication.
//   Lane 63's dummy rows get c3=c4=1 via dB=0 at phase 1 (replaces row clamp).
// R6 lesson: the serial wave is single-wave ISSUE-bound (~2cy/instr); this moves
// ~13 instr/body (coeff+clamp math) into the parallel phase.

#define NB 16

__device__ __forceinline__ float wave_shr1_or_one(float v) {
    // lane i <- v[lane i-1]; lane 0 <- 1.0f (bound_ctrl=false keeps 'old' operand)
    const int one = 0x3f800000;
    int r = __builtin_amdgcn_update_dpp(one, __float_as_int(v),
                                        0x138 /*wave_shr:1*/, 0xF, 0xF, false);
    return __int_as_float(r);
}

__global__ __launch_bounds__(256)
void sigkernel_kernel(const float* __restrict__ xs,
                      const float* __restrict__ ys,
                      float* __restrict__ out)
{
    __shared__ float sx[128][9];          // padded rows (phase-1 scalar reads)
    __shared__ float sy[128 * 8];         // contiguous [q][8] for float4 broadcast
    __shared__ float xsq[128];
    __shared__ float ysq[128];
    __shared__ float CF[64 * 128 * 4 + 4];  // coeff quads + trailing (1,1,1,1) slot

    const int t  = threadIdx.x;
    const int bx = blockIdx.x;
    const int by = blockIdx.y;
    const float* xp = xs + bx * 1024;
    const float* yp = ys + by * 1024;

    for (int e = t; e < 1024; e += 256) {
        sx[e >> 3][e & 7] = xp[e];
        sy[e] = yp[e];
    }
    __syncthreads();

    if (t < 128) {
        float s = 0.f;
        #pragma unroll
        for (int k = 0; k < 8; ++k) s += sx[t][k] * sx[t][k];
        xsq[t] = s;
    } else {
        const int q = t - 128;
        float s = 0.f;
        #pragma unroll
        for (int k = 0; k < 8; ++k) s += sy[q * 8 + k] * sy[q * 8 + k];
        ysq[q] = s;
    }
    if (t == 0) { CF[32768] = 1.f; CF[32769] = 1.f; CF[32770] = 1.f; CF[32771] = 1.f; }
    __syncthreads();

    // ---- phase 1: coefficients straight from dots (K never stored) ----
    {
        const int l = t & 63, w = t >> 6;
        const int r0 = 2 * l, r1 = 2 * l + 1;
        const int r2 = (2 * l + 2 > 127) ? 127 : 2 * l + 2;   // lane63: masked below
        float xr0[8], xr1[8], xr2[8];
        #pragma unroll
        for (int k = 0; k < 8; ++k) {
            xr0[k] = sx[r0][k]; xr1[k] = sx[r1][k]; xr2[k] = sx[r2][k];
        }
        const float xq0 = xsq[r0], xq1 = xsq[r1], xq2 = xsq[r2];
        const float4* SYv = (const float4*)sy;
        float4* CFv = (float4*)CF;

        for (int c = 0; c < 4; ++c) {
            const int g = w + 4 * c;        // 0..15
            const int q0 = 8 * g;
            float K0[9], K1[9], K2[9];
            #pragma unroll
            for (int jj = 0; jj < 9; ++jj) {
                int qc = q0 + jj; if (qc > 127) qc = 127;     // only g=15,jj=8
                const float4 ya = SYv[qc * 2];                // broadcast reads
                const float4 yb = SYv[qc * 2 + 1];
                const float yc = ysq[qc];
                float d0 = xr0[0]*ya.x + xr0[1]*ya.y + xr0[2]*ya.z + xr0[3]*ya.w
                         + xr0[4]*yb.x + xr0[5]*yb.y + xr0[6]*yb.z + xr0[7]*yb.w;
                float d1 = xr1[0]*ya.x + xr1[1]*ya.y + xr1[2]*ya.z + xr1[3]*ya.w
                         + xr1[4]*yb.x + xr1[5]*yb.y + xr1[6]*yb.z + xr1[7]*yb.w;
                float d2 = xr2[0]*ya.x + xr2[1]*ya.y + xr2[2]*ya.z + xr2[3]*ya.w
                         + xr2[4]*yb.x + xr2[5]*yb.y + xr2[6]*yb.z + xr2[7]*yb.w;
                K0[jj] = expf(-0.5f * (xq0 + yc - 2.0f * d0));
                K1[jj] = expf(-0.5f * (xq1 + yc - 2.0f * d1));
                K2[jj] = expf(-0.5f * (xq2 + yc - 2.0f * d2));
            }
            #pragma unroll
            for (int m = 0; m < 8; ++m) {
                const int q = q0 + m;
                if (q > 126) continue;                        // only g=15,m=7
                const float dA = K1[m + 1] + K0[m] - K1[m] - K0[m + 1];
                float dB = K2[m + 1] + K1[m] - K2[m] - K1[m + 1];
                if (l == 63) dB = 0.f;                        // dummy row 127 -> inert
                const float iA = 0.25f * dA, iB = 0.25f * dB;
                const float eA = iA * iA * (1.0f / 12.0f);
                const float eB = iB * iB * (1.0f / 12.0f);
                float4 qd;
                qd.x = 1.0f + 0.5f * iA + eA;   // c1 row 2l
                qd.y = 1.0f - eA;               // c2 row 2l
                qd.z = 1.0f + 0.5f * iB + eB;   // c1 row 2l+1
                qd.w = 1.0f - eB;               // c2 row 2l+1
                CFv[l * 128 + ((q + 2 * l) & 127)] = qd;
            }
        }
    }
    __syncthreads();

    // ---- phase 2: waves 1..3 done; wave 0 runs the register wavefront ----
    if (t >= 64) return;

    const int l = t;
    const float4* CFv = (const float4*)CF;

    float cur0 = 1.f, cur1 = 1.f, cur2 = 1.f, cur3 = 1.f;  // rows 4l+1..4l+4, col j-1
    float h0 = 1.f, h1 = 1.f, h2 = 1.f;                    // neighbor row-4l history

    // body k: dyadic col q = k-l; quad at CFv[l*128 + ((k+l)&127)], OOB -> ones slot
#define LDQ(dst, kk)                                             \
    {                                                            \
        const int q_ = (kk) - l;                                 \
        const int idx = ((unsigned)q_ <= 126u)                   \
                        ? (l * 128 + (((kk) + l) & 127)) : 8192; \
        dst = CFv[idx];                                          \
    }

#define SUBSTEP(c1, c2, c3, c4)                                  \
    {                                                            \
        const float n0 = (h1 + cur0) * (c1) - h2   * (c2);       \
        const float n1 = (n0 + cur1) * (c1) - cur0 * (c2);       \
        const float n2 = (n1 + cur2) * (c3) - cur1 * (c4);       \
        const float n3 = (n2 + cur3) * (c3) - cur2 * (c4);       \
        cur0 = n0; cur1 = n1; cur2 = n2; cur3 = n3;              \
        const float sh = wave_shr1_or_one(n3);                   \
        h2 = h1; h1 = h0; h0 = sh;                               \
    }

#define BODYQ(Q)                                                 \
    {                                                            \
        const float c1 = Q.x, c2 = Q.y, c3 = Q.z, c4 = Q.w;      \
        SUBSTEP(c1, c2, c3, c4);                                 \
        SUBSTEP(c1, c2, c3, c4);                                 \
    }

    float4 A0, A1, A2;            // 3-deep static prefetch (~2 bodies of slack)
    LDQ(A0, 0);
    LDQ(A1, 1);
    LDQ(A2, 2);

    // 63 iterations x 3 bodies = 189, + 1 tail body = 190 bodies = substeps 1..380
    for (int m = 0; m < 63; ++m) {
        const int k = 3 * m;
        { BODYQ(A0); LDQ(A0, k + 3); }
        { BODYQ(A1); LDQ(A1, k + 4); }
        { BODYQ(A2); LDQ(A2, k + 5); }
    }
    BODYQ(A0);                    // body 189 (quad loaded at m=62)

    // K[254][254]: row 254 = lane 63's second row, finished at substep 380
    if (l == 63) out[bx * NB + by] = cur1;
}

extern "C" void kernel_launch(void* const* d_in, const int* in_sizes, int n_in,
                              void* d_out, int out_size, void* d_ws, size_t ws_size,
                              hipStream_t stream)
{
    const float* xs = (const float*)d_in[0];
    const float* ys = (const float*)d_in[1];
    float* out = (float*)d_out;
    dim3 grid(NB, NB);
    dim3 block(256);
    hipLaunchKernelGGL(sigkernel_kernel, grid, block, 0, stream, xs, ys, out);
}